// Round 1
// baseline (935.793 us; speedup 1.0000x reference)
//
#include <hip/hip_runtime.h>
#include <cstdint>
#include <cstddef>

// ---------------------------------------------------------------------------
// OppoModelNet: GNN forward
//   encoder (256->512->256) -> LSTM step (256) -> nf (128)
//   edge MLP via linear split: P=nf@we_L^T, Q=nf@we_R^T+be,
//     Hsum[n] = sum_{e:dst=n} relu(P[src_e]+Q[n])   (counting-sorted, no atomics)
//     agg = Hsum@we2^T + deg*be2
//   node MLP (256->256->128) -> readout (128->256->8)
// All GEMMs: bf16 MFMA 16x16x32, fp32 accumulate.
// R1: 128x128-tile GEMM with global_load_lds width-16 staging (m97 structure);
//     gates_lstm staging switched to global_load_lds.
// ---------------------------------------------------------------------------

#define NN 65536      // nodes
#define NE 524288     // edges

typedef __bf16 bf16x8 __attribute__((ext_vector_type(8)));
typedef float  f32x4  __attribute__((ext_vector_type(4)));

typedef __attribute__((address_space(1))) unsigned int glb_uint;
typedef __attribute__((address_space(3))) unsigned int lds_uint;

// async global->LDS DMA, 16B per lane. LDS dest must be wave-uniform;
// HW places lane l's 16B at lds + l*16.
__device__ __forceinline__ void async16(const void* g, void* l){
  __builtin_amdgcn_global_load_lds((glb_uint*)g, (lds_uint*)l, 16, 0, 0);
}

__device__ __forceinline__ float bf2f(unsigned short u){
  union { unsigned int i; float f; } v; v.i = ((unsigned int)u) << 16; return v.f;
}
__device__ __forceinline__ unsigned short f2b(float f){
  union { float f; unsigned int i; } v; v.f = f;
  unsigned int r = v.i + 0x7FFFu + ((v.i >> 16) & 1u);
  return (unsigned short)(r >> 16);
}
__device__ __forceinline__ float sigm(float x){ return 1.f/(1.f+__expf(-x)); }

// ---------------------------------------------------------------------------
// batched fp32 -> bf16 conversion
// ---------------------------------------------------------------------------
struct ConvArgs {
  const float* s[14];
  unsigned short* d[14];
  int n4[14];
  int cnt;
};

__global__ __launch_bounds__(256) void convert_kernel(ConvArgs a){
  int stride = gridDim.x * blockDim.x;
  int gid = blockIdx.x * blockDim.x + threadIdx.x;
  for (int seg = 0; seg < a.cnt; ++seg){
    const float4* s = (const float4*)a.s[seg];
    ushort4* d = (ushort4*)a.d[seg];
    int n4 = a.n4[seg];
    for (int i = gid; i < n4; i += stride){
      float4 v = s[i];
      ushort4 o; o.x=f2b(v.x); o.y=f2b(v.y); o.z=f2b(v.z); o.w=f2b(v.w);
      d[i] = o;
    }
  }
}

// ---------------------------------------------------------------------------
// generic bf16 GEMM: C[M,Nc] = act(A[M,K] @ B[Nc,K]^T + biasmode), bf16 out
// m97 structure: tile 128x128, BK=32, 256 threads = 4 waves in 2x2,
// each wave 64x64 out (4x4 frags of 16x16), global_load_lds staging.
// LDS layout: 8 groups of 512 shorts; group g holds rows g*16..g*16+15:
//   As[g*512 + c*128 + r*8 + ki] = A[m0+g*16+r][kt + c*8 + ki]
// which is exactly lane l -> offset l*8 shorts with r=l&15, c=l>>4, so the
// DMA's fixed (base + lane*16B) placement IS the MFMA fragment layout.
// RSCALE: bias[col] * (float)rs[row]   (deg-scaled bias for agg GEMM)
// ---------------------------------------------------------------------------
template<int ACT, int RSCALE>
__global__ __launch_bounds__(256) void gemm_kernel(
    const unsigned short* __restrict__ A, int lda,
    const unsigned short* __restrict__ B, int ldb, int K,
    const float* __restrict__ bias,
    const int* __restrict__ rs,
    unsigned short* __restrict__ C, int ldc)
{
  __shared__ alignas(16) unsigned short As[4096];   // 128 rows x 32 k
  __shared__ alignas(16) unsigned short Bs[4096];
  int t = threadIdx.x, wave = t >> 6, lane = t & 63;
  int m0 = blockIdx.x * 128, n0 = blockIdx.y * 128;
  int wr = wave >> 1, wc = wave & 1;                // 2x2 wave grid

  f32x4 acc[4][4] = {};                             // [m][n]

  // staging: wave w DMAs A groups {w, w+4} and B groups {w, w+4}
  int srow = lane & 15, schunk = lane >> 4;
  const unsigned short* Ap0 = A + (size_t)(m0 + wave * 16 + srow) * lda + schunk * 8;
  const unsigned short* Ap1 = Ap0 + (size_t)64 * lda;
  const unsigned short* Bp0 = B + (size_t)(n0 + wave * 16 + srow) * ldb + schunk * 8;
  const unsigned short* Bp1 = Bp0 + (size_t)64 * ldb;
  unsigned short* AsW0 = &As[(wave)     << 9];
  unsigned short* AsW1 = &As[(wave + 4) << 9];
  unsigned short* BsW0 = &Bs[(wave)     << 9];
  unsigned short* BsW1 = &Bs[(wave + 4) << 9];

  for (int kt = 0; kt < K; kt += 32){
    __syncthreads();                       // prev reads done before overwrite
    async16(Ap0 + kt, AsW0);
    async16(Ap1 + kt, AsW1);
    async16(Bp0 + kt, BsW0);
    async16(Bp1 + kt, BsW1);
    __syncthreads();                       // drains vmcnt before s_barrier
    int fo = (schunk << 7) + (srow << 3);
    bf16x8 a[4], b[4];
#pragma unroll
    for (int m = 0; m < 4; ++m) a[m] = *(const bf16x8*)&As[((wr * 4 + m) << 9) + fo];
#pragma unroll
    for (int n = 0; n < 4; ++n) b[n] = *(const bf16x8*)&Bs[((wc * 4 + n) << 9) + fo];
#pragma unroll
    for (int m = 0; m < 4; ++m)
#pragma unroll
      for (int n = 0; n < 4; ++n)
        acc[m][n] = __builtin_amdgcn_mfma_f32_16x16x32_bf16(a[m], b[n], acc[m][n], 0, 0, 0);
  }

  int coll = lane & 15, rq = lane >> 4;
#pragma unroll
  for (int n = 0; n < 4; ++n){
    int col = n0 + wc * 64 + n * 16 + coll;
    float bv = bias[col];
#pragma unroll
    for (int m = 0; m < 4; ++m){
#pragma unroll
      for (int r = 0; r < 4; ++r){
        int rrow = m0 + wr * 64 + m * 16 + rq * 4 + r;
        float scale = RSCALE ? (float)rs[rrow] : 1.0f;
        float v = acc[m][n][r] + bv * scale;
        if (ACT) v = fmaxf(v, 0.f);
        C[(size_t)rrow * ldc + col] = f2b(v);
      }
    }
  }
}

// ---------------------------------------------------------------------------
// gates = [x|h0] @ [w_ih|w_hh]^T + b ; LSTM elementwise fused in registers.
// 64 rows x 64 cols x 4 gates per block; global_load_lds staging.
// ---------------------------------------------------------------------------
__global__ __launch_bounds__(256) void gates_lstm_kernel(
    const unsigned short* __restrict__ Xb,   // [N,256] bf16
    const unsigned short* __restrict__ H0b,  // [N,256] bf16
    const unsigned short* __restrict__ Wih,  // [1024][256] bf16
    const unsigned short* __restrict__ Whh,  // [1024][256] bf16
    const float* __restrict__ b_ih, const float* __restrict__ b_hh,
    const float* __restrict__ c0,            // [N,256] fp32
    float* __restrict__ h1o, float* __restrict__ c1o,  // fp32 outputs
    unsigned short* __restrict__ rb)         // relu(h1) bf16 [N,256]
{
  __shared__ alignas(16) unsigned short As[2048];
  __shared__ alignas(16) unsigned short Bs[4][2048];
  int t = threadIdx.x, wave = t >> 6, lane = t & 63;
  int m0 = blockIdx.x * 64, cb = blockIdx.y * 64;
  int srow = lane & 15, schunk = lane >> 4;

  f32x4 acc[4][4] = {};

  for (int kt = 0; kt < 512; kt += 32){
    const unsigned short* Abase = (kt < 256) ? (Xb + kt) : (H0b + (kt - 256));
    const unsigned short* Wbase = (kt < 256) ? (Wih + kt) : (Whh + (kt - 256));
    __syncthreads();
    async16(Abase + (size_t)(m0 + wave * 16 + srow) * 256 + schunk * 8, &As[wave << 9]);
#pragma unroll
    for (int g = 0; g < 4; ++g){
      async16(Wbase + (size_t)(g * 256 + cb + wave * 16 + srow) * 256 + schunk * 8,
              &Bs[g][wave << 9]);
    }
    __syncthreads();
    bf16x8 a = *(const bf16x8*)&As[(wave << 9) + (schunk << 7) + (srow << 3)];
#pragma unroll
    for (int g = 0; g < 4; ++g){
#pragma unroll
      for (int j = 0; j < 4; ++j){
        bf16x8 b = *(const bf16x8*)&Bs[g][(j << 9) + (schunk << 7) + (srow << 3)];
        acc[g][j] = __builtin_amdgcn_mfma_f32_16x16x32_bf16(a, b, acc[g][j], 0, 0, 0);
      }
    }
  }

  int coll = lane & 15, rq = lane >> 4;
#pragma unroll
  for (int j = 0; j < 4; ++j){
    int col = cb + j * 16 + coll;
    float bi  = b_ih[col]       + b_hh[col];
    float bff = b_ih[256 + col] + b_hh[256 + col];
    float bg  = b_ih[512 + col] + b_hh[512 + col];
    float bo  = b_ih[768 + col] + b_hh[768 + col];
#pragma unroll
    for (int r = 0; r < 4; ++r){
      int node = m0 + wave * 16 + rq * 4 + r;
      size_t off = (size_t)node * 256 + col;
      float iv = sigm(acc[0][j][r] + bi);
      float fv = sigm(acc[1][j][r] + bff);
      float gv = tanhf(acc[2][j][r] + bg);
      float ov = sigm(acc[3][j][r] + bo);
      float cv = fv * c0[off] + iv * gv;
      float hv = ov * tanhf(cv);
      h1o[off] = hv;
      c1o[off] = cv;
      rb[off] = f2b(fmaxf(hv, 0.f));
    }
  }
}

// ---------------------------------------------------------------------------
// counting sort by dst: hist -> scan -> scatter
// ---------------------------------------------------------------------------
__global__ __launch_bounds__(256) void hist_kernel(
    const int* __restrict__ dst, int* __restrict__ hist)
{
  int e = blockIdx.x * 256 + threadIdx.x;
  atomicAdd(&hist[dst[e]], 1);
}

__global__ __launch_bounds__(256) void scan1_kernel(
    const int* __restrict__ hist, int* __restrict__ offs, int* __restrict__ bsum)
{
  __shared__ int s[256];
  int b = blockIdx.x, t = threadIdx.x;
  int v = hist[b * 256 + t];
  s[t] = v; __syncthreads();
  for (int d = 1; d < 256; d <<= 1){
    int x = (t >= d) ? s[t - d] : 0;
    __syncthreads();
    s[t] += x;
    __syncthreads();
  }
  offs[b * 256 + t] = s[t] - v;
  if (t == 255) bsum[b] = s[255];
}

__global__ __launch_bounds__(256) void scan2_kernel(int* __restrict__ bsum){
  __shared__ int s[256];
  int t = threadIdx.x;
  int v = bsum[t];
  s[t] = v; __syncthreads();
  for (int d = 1; d < 256; d <<= 1){
    int x = (t >= d) ? s[t - d] : 0;
    __syncthreads();
    s[t] += x;
    __syncthreads();
  }
  bsum[t] = s[t] - v;
}

__global__ __launch_bounds__(256) void scan3_kernel(
    int* __restrict__ offs, const int* __restrict__ bsum, int* __restrict__ cursor)
{
  int i = blockIdx.x * 256 + threadIdx.x;
  int v = offs[i] + bsum[blockIdx.x];
  offs[i] = v;
  cursor[i] = v;
}

__global__ __launch_bounds__(256) void scatter_kernel(
    const int* __restrict__ src, const int* __restrict__ dst,
    int* __restrict__ cursor, int* __restrict__ sorted_src)
{
  int e = blockIdx.x * 256 + threadIdx.x;
  int d = dst[e];
  int pos = atomicAdd(&cursor[d], 1);
  sorted_src[pos] = src[e];
}

// ---------------------------------------------------------------------------
// per-node edge aggregation: Hsum[n] = sum_{e in edges(n)} relu(P[src_e]+Q[n])
// one wave per node, 4 dims/lane. No atomics; src rows graph-local (L2-hot).
// ---------------------------------------------------------------------------
__global__ __launch_bounds__(256) void edge_agg_kernel(
    const unsigned short* __restrict__ P,    // [N,256] bf16
    const unsigned short* __restrict__ Q,    // [N,256] bf16 (bias folded in)
    const int* __restrict__ sorted_src,
    const int* __restrict__ offs,
    const int* __restrict__ cnt,
    unsigned short* __restrict__ Hsum)       // [N,256] bf16
{
  int t = threadIdx.x;
  int n = (blockIdx.x << 2) + (t >> 6);
  int lane = t & 63;
  int d0 = lane * 4;
  int off = offs[n], c = cnt[n];
  ushort4 qv = *(const ushort4*)&Q[(size_t)n * 256 + d0];
  float q0 = bf2f(qv.x), q1 = bf2f(qv.y), q2 = bf2f(qv.z), q3 = bf2f(qv.w);
  float a0 = 0.f, a1 = 0.f, a2 = 0.f, a3 = 0.f;
  for (int i = 0; i < c; ++i){
    int s = sorted_src[off + i];
    ushort4 pv = *(const ushort4*)&P[(size_t)s * 256 + d0];
    a0 += fmaxf(bf2f(pv.x) + q0, 0.f);
    a1 += fmaxf(bf2f(pv.y) + q1, 0.f);
    a2 += fmaxf(bf2f(pv.z) + q2, 0.f);
    a3 += fmaxf(bf2f(pv.w) + q3, 0.f);
  }
  ushort4 o; o.x = f2b(a0); o.y = f2b(a1); o.z = f2b(a2); o.w = f2b(a3);
  *(ushort4*)&Hsum[(size_t)n * 256 + d0] = o;
}

// ---------------------------------------------------------------------------
// readout layer 2: logits[N,8] = rh[N,256] @ wr2[8,256]^T + br2  (fp32 out)
// ---------------------------------------------------------------------------
__global__ __launch_bounds__(256) void logits_kernel(
    const unsigned short* __restrict__ rh,
    const unsigned short* __restrict__ wr2b,
    const float* __restrict__ br2,
    float* __restrict__ out)
{
  __shared__ alignas(16) unsigned short W[2048];
  int t = threadIdx.x;
  *(uint4*)&W[t * 8] = *(const uint4*)&wr2b[t * 8];
  __syncthreads();
  int node = blockIdx.x * 32 + (t >> 3);
  int o = t & 7;
  const unsigned short* r = rh + (size_t)node * 256;
  float s = br2[o];
#pragma unroll
  for (int k = 0; k < 256; k += 8){
    uint4 av = *(const uint4*)&r[k];
    const unsigned short* ap = (const unsigned short*)&av;
#pragma unroll
    for (int i = 0; i < 8; ++i) s += bf2f(ap[i]) * bf2f(W[o * 256 + k + i]);
  }
  out[(size_t)node * 8 + o] = s;
}

// ---------------------------------------------------------------------------
extern "C" void kernel_launch(void* const* d_in, const int* in_sizes, int n_in,
                              void* d_out, int out_size, void* d_ws, size_t ws_size,
                              hipStream_t stream)
{
  (void)in_sizes; (void)n_in; (void)out_size; (void)ws_size;
  const float* obs = (const float*)d_in[0];
  const float* h0  = (const float*)d_in[1];
  const float* c0  = (const float*)d_in[2];
  const int*   src = (const int*)d_in[3];
  const int*   dst = (const int*)d_in[4];
  const float* w1a = (const float*)d_in[5];
  const float* b1a = (const float*)d_in[6];
  const float* w1b = (const float*)d_in[7];
  const float* b1b = (const float*)d_in[8];
  const float* wih = (const float*)d_in[9];
  const float* bih = (const float*)d_in[10];
  const float* whh = (const float*)d_in[11];
  const float* bhh = (const float*)d_in[12];
  const float* w1  = (const float*)d_in[13];
  const float* b1  = (const float*)d_in[14];
  const float* we  = (const float*)d_in[15];
  const float* be  = (const float*)d_in[16];
  const float* we2 = (const float*)d_in[17];
  const float* be2 = (const float*)d_in[18];
  const float* wn  = (const float*)d_in[19];
  const float* bn  = (const float*)d_in[20];
  const float* wn2 = (const float*)d_in[21];
  const float* bn2 = (const float*)d_in[22];
  const float* wr  = (const float*)d_in[23];
  const float* br  = (const float*)d_in[24];
  const float* wr2 = (const float*)d_in[25];
  const float* br2 = (const float*)d_in[26];

  char* ws = (char*)d_ws;
  typedef unsigned short u16;
  // bf16 weight copies + sort scratch
  u16* w1a_b = (u16*)(ws + 0);
  u16* w1b_b = (u16*)(ws + 262144);
  u16* wih_b = (u16*)(ws + 524288);
  u16* whh_b = (u16*)(ws + 1048576);
  u16* w1_b  = (u16*)(ws + 1572864);
  u16* we_b  = (u16*)(ws + 1638400);
  u16* we2_b = (u16*)(ws + 1769472);
  u16* wn_b  = (u16*)(ws + 1835008);
  u16* wn2_b = (u16*)(ws + 1966080);
  u16* wr_b  = (u16*)(ws + 2031616);
  u16* wr2_b = (u16*)(ws + 2097152);
  float* zbias = (float*)(ws + 2101248);        // 512 fp32 zeros
  int* hist    = (int*)(ws + 2103296);          // [65536] = deg
  int* offs    = (int*)(ws + 2365440);          // [65536]
  int* cursor  = (int*)(ws + 2627584);          // [65536]
  int* bsum    = (int*)(ws + 2889728);          // [256]
  int* ssrc    = (int*)(ws + 2890752);          // sorted_src [524288]

  // aliased activation regions
  char* RA = ws + 5242880;    // 33.5MB: obs_b -> x_b -> P -> nf2
  char* RB = ws + 38797312;   // 33.5MB: h0_b -> Hsum -> hidn -> rh
  char* RY = ws + 72351744;   // 67MB:   y1 -> [rb->Q | ninp]

  u16* obs_b = (u16*)RA;
  u16* x_b   = (u16*)RA;
  u16* P     = (u16*)RA;
  u16* nf2   = (u16*)RA;
  u16* h0_b  = (u16*)RB;
  u16* Hsum  = (u16*)RB;
  u16* hidn  = (u16*)RB;
  u16* rh    = (u16*)RB;
  u16* y1    = (u16*)RY;
  u16* rb    = (u16*)RY;
  u16* Q     = (u16*)RY;
  u16* ninp  = (u16*)(RY + 33554432);

  float* logits = (float*)d_out;
  float* h1o = logits + (size_t)NN * 8;
  float* c1o = h1o + (size_t)NN * 256;

  // 0) zero-init scratch
  (void)hipMemsetAsync(zbias, 0, 2048, stream);
  (void)hipMemsetAsync(hist, 0, 65536 * 4, stream);

  // 1) convert fp32 -> bf16
  ConvArgs ca;
  const float* ss[13] = {obs, h0, w1a, w1b, wih, whh, w1, we, we2, wn, wn2, wr, wr2};
  u16* dd[13] = {obs_b, h0_b, w1a_b, w1b_b, wih_b, whh_b, w1_b, we_b, we2_b, wn_b, wn2_b, wr_b, wr2_b};
  int nn[13] = {NN*256, NN*256, 512*256, 256*512, 1024*256, 1024*256, 128*256,
                256*256, 128*256, 256*256, 128*256, 256*128, 8*256};
  for (int i = 0; i < 13; ++i){ ca.s[i]=ss[i]; ca.d[i]=dd[i]; ca.n4[i]=nn[i]/4; }
  ca.cnt = 13;
  convert_kernel<<<2048, 256, 0, stream>>>(ca);

  // 2) counting sort of edges by dst (independent of GEMM chain)
  hist_kernel<<<NE/256, 256, 0, stream>>>(dst, hist);
  scan1_kernel<<<256, 256, 0, stream>>>(hist, offs, bsum);
  scan2_kernel<<<1, 256, 0, stream>>>(bsum);
  scan3_kernel<<<256, 256, 0, stream>>>(offs, bsum, cursor);
  scatter_kernel<<<NE/256, 256, 0, stream>>>(src, dst, cursor, ssrc);

  // 3) y1 = relu(obs @ w1a^T + b1a)   [N,512]
  gemm_kernel<1,0><<<dim3(NN/128, 4), 256, 0, stream>>>(obs_b, 256, w1a_b, 256, 256, b1a, nullptr, y1, 512);
  // 4) x = y1 @ w1b^T + b1b           [N,256]
  gemm_kernel<0,0><<<dim3(NN/128, 2), 256, 0, stream>>>(y1, 512, w1b_b, 512, 512, b1b, nullptr, x_b, 256);
  // 5) gates + LSTM fused -> h1, c1 (fp32 out), rb = relu(h1) bf16
  gates_lstm_kernel<<<dim3(NN/64, 4), 256, 0, stream>>>(
      x_b, h0_b, wih_b, whh_b, bih, bhh, c0, h1o, c1o, rb);
  // 6) nf = rb @ w1^T + b1 -> ninp cols 0..127 (ldc=256)
  gemm_kernel<0,0><<<dim3(NN/128, 1), 256, 0, stream>>>(rb, 256, w1_b, 256, 256, b1, nullptr, ninp, 256);
  // 7) P = nf @ we_L^T (zero bias)    [N,256], K=128
  gemm_kernel<0,0><<<dim3(NN/128, 2), 256, 0, stream>>>(ninp, 256, we_b, 256, 128, zbias, nullptr, P, 256);
  // 8) Q = nf @ we_R^T + be           [N,256], K=128
  gemm_kernel<0,0><<<dim3(NN/128, 2), 256, 0, stream>>>(ninp, 256, we_b + 128, 256, 128, be, nullptr, Q, 256);
  // 9) Hsum[n] = sum over edges relu(P[src]+Q[n])
  edge_agg_kernel<<<NN/4, 256, 0, stream>>>(P, Q, ssrc, offs, hist, Hsum);
  // 10) agg = Hsum @ we2^T + deg*be2 -> ninp cols 128..255
  gemm_kernel<0,1><<<dim3(NN/128, 1), 256, 0, stream>>>(Hsum, 256, we2_b, 256, 256, be2, hist, ninp + 128, 256);
  // 11) hidn = relu(ninp @ wn^T + bn)  [N,256]
  gemm_kernel<1,0><<<dim3(NN/128, 2), 256, 0, stream>>>(ninp, 256, wn_b, 256, 256, bn, nullptr, hidn, 256);
  // 12) nf2 = hidn @ wn2^T + bn2       [N,128]
  gemm_kernel<0,0><<<dim3(NN/128, 1), 256, 0, stream>>>(hidn, 256, wn2_b, 256, 256, bn2, nullptr, nf2, 128);
  // 13) rh = relu(nf2 @ wr^T + br)     [N,256]
  gemm_kernel<1,0><<<dim3(NN/128, 2), 256, 0, stream>>>(nf2, 128, wr_b, 128, 128, br, nullptr, rh, 256);
  // 14) logits = rh @ wr2^T + br2      [N,8] fp32
  logits_kernel<<<NN/32, 256, 0, stream>>>(rh, wr2_b, br2, logits);
}

// Round 2
// 923.745 us; speedup vs baseline: 1.0130x; 1.0130x over previous
//
#include <hip/hip_runtime.h>
#include <cstdint>
#include <cstddef>

// ---------------------------------------------------------------------------
// OppoModelNet: GNN forward
//   encoder (256->512->256) -> LSTM step (256) -> nf (128)
//   edge MLP via linear split: P=nf@we_L^T, Q=nf@we_R^T+be,
//     Hsum[n] = sum_{e:dst=n} relu(P[src_e]+Q[n])   (counting-sorted, no atomics)
//     agg = Hsum@we2^T + deg*be2
//   node MLP (256->256->128) -> readout (128->256->8)
// All GEMMs: bf16 MFMA 16x16x32, fp32 accumulate.
// R2: 2-phase double-buffered global_load_lds staging (stage next tile
//     BEFORE computing current; one barrier per K-step) in gemm + gates.
// ---------------------------------------------------------------------------

#define NN 65536      // nodes
#define NE 524288     // edges

typedef __bf16 bf16x8 __attribute__((ext_vector_type(8)));
typedef float  f32x4  __attribute__((ext_vector_type(4)));

typedef __attribute__((address_space(1))) unsigned int glb_uint;
typedef __attribute__((address_space(3))) unsigned int lds_uint;

// async global->LDS DMA, 16B per lane. LDS dest must be wave-uniform;
// HW places lane l's 16B at lds + l*16.
__device__ __forceinline__ void async16(const void* g, void* l){
  __builtin_amdgcn_global_load_lds((glb_uint*)g, (lds_uint*)l, 16, 0, 0);
}

__device__ __forceinline__ float bf2f(unsigned short u){
  union { unsigned int i; float f; } v; v.i = ((unsigned int)u) << 16; return v.f;
}
__device__ __forceinline__ unsigned short f2b(float f){
  union { float f; unsigned int i; } v; v.f = f;
  unsigned int r = v.i + 0x7FFFu + ((v.i >> 16) & 1u);
  return (unsigned short)(r >> 16);
}
__device__ __forceinline__ float sigm(float x){ return 1.f/(1.f+__expf(-x)); }

// ---------------------------------------------------------------------------
// batched fp32 -> bf16 conversion
// ---------------------------------------------------------------------------
struct ConvArgs {
  const float* s[14];
  unsigned short* d[14];
  int n4[14];
  int cnt;
};

__global__ __launch_bounds__(256) void convert_kernel(ConvArgs a){
  int stride = gridDim.x * blockDim.x;
  int gid = blockIdx.x * blockDim.x + threadIdx.x;
  for (int seg = 0; seg < a.cnt; ++seg){
    const float4* s = (const float4*)a.s[seg];
    ushort4* d = (ushort4*)a.d[seg];
    int n4 = a.n4[seg];
    for (int i = gid; i < n4; i += stride){
      float4 v = s[i];
      ushort4 o; o.x=f2b(v.x); o.y=f2b(v.y); o.z=f2b(v.z); o.w=f2b(v.w);
      d[i] = o;
    }
  }
}

// ---------------------------------------------------------------------------
// generic bf16 GEMM: C[M,Nc] = act(A[M,K] @ B[Nc,K]^T + biasmode), bf16 out
// 128x128 tile, BK=32, 256 threads = 4 waves in 2x2, each wave 64x64 out.
// 2-phase double-buffered global_load_lds staging: stage tile k+1 into
// buf^1, compute tile k from buf, single barrier per K-step (drains vmcnt).
// LDS group layout: group g (512 shorts) holds rows g*16..g*16+15:
//   lane l's 16B lands at l*16 -> row l&15, k-chunk l>>4 == fragment layout.
// RSCALE: bias[col] * (float)rs[row]   (deg-scaled bias for agg GEMM)
// ---------------------------------------------------------------------------
template<int ACT, int RSCALE>
__global__ __launch_bounds__(256) void gemm_kernel(
    const unsigned short* __restrict__ A, int lda,
    const unsigned short* __restrict__ B, int ldb, int K,
    const float* __restrict__ bias,
    const int* __restrict__ rs,
    unsigned short* __restrict__ C, int ldc)
{
  __shared__ alignas(16) unsigned short As[2][4096];   // 2 x (128 rows x 32 k)
  __shared__ alignas(16) unsigned short Bs[2][4096];
  int t = threadIdx.x, wave = t >> 6, lane = t & 63;
  int m0 = blockIdx.x * 128, n0 = blockIdx.y * 128;
  int wr = wave >> 1, wc = wave & 1;                // 2x2 wave grid

  f32x4 acc[4][4] = {};                             // [m][n]

  int srow = lane & 15, schunk = lane >> 4;
  const unsigned short* Ap0 = A + (size_t)(m0 + wave * 16 + srow) * lda + schunk * 8;
  const unsigned short* Ap1 = Ap0 + (size_t)64 * lda;
  const unsigned short* Bp0 = B + (size_t)(n0 + wave * 16 + srow) * ldb + schunk * 8;
  const unsigned short* Bp1 = Bp0 + (size_t)64 * ldb;

  auto stage = [&](int b, int kt){
    async16(Ap0 + kt, &As[b][(wave)     << 9]);
    async16(Ap1 + kt, &As[b][(wave + 4) << 9]);
    async16(Bp0 + kt, &Bs[b][(wave)     << 9]);
    async16(Bp1 + kt, &Bs[b][(wave + 4) << 9]);
  };
  int fo = (schunk << 7) + (srow << 3);
  auto compute = [&](int b){
    bf16x8 av[4], bv[4];
#pragma unroll
    for (int m = 0; m < 4; ++m) av[m] = *(const bf16x8*)&As[b][((wr * 4 + m) << 9) + fo];
#pragma unroll
    for (int n = 0; n < 4; ++n) bv[n] = *(const bf16x8*)&Bs[b][((wc * 4 + n) << 9) + fo];
#pragma unroll
    for (int m = 0; m < 4; ++m)
#pragma unroll
      for (int n = 0; n < 4; ++n)
        acc[m][n] = __builtin_amdgcn_mfma_f32_16x16x32_bf16(av[m], bv[n], acc[m][n], 0, 0, 0);
  };

  stage(0, 0);
  __syncthreads();                        // buf0 ready
  int cur = 0;
  for (int kt = 32; kt < K; kt += 32){
    stage(cur ^ 1, kt);                   // DMA next tile (flies during MFMA)
    compute(cur);
    __syncthreads();                      // drains vmcnt -> next buf ready
    cur ^= 1;
  }
  compute(cur);                           // last tile

  int coll = lane & 15, rq = lane >> 4;
#pragma unroll
  for (int n = 0; n < 4; ++n){
    int col = n0 + wc * 64 + n * 16 + coll;
    float bv = bias[col];
#pragma unroll
    for (int m = 0; m < 4; ++m){
#pragma unroll
      for (int r = 0; r < 4; ++r){
        int rrow = m0 + wr * 64 + m * 16 + rq * 4 + r;
        float scale = RSCALE ? (float)rs[rrow] : 1.0f;
        float v = acc[m][n][r] + bv * scale;
        if (ACT) v = fmaxf(v, 0.f);
        C[(size_t)rrow * ldc + col] = f2b(v);
      }
    }
  }
}

// ---------------------------------------------------------------------------
// gates = [x|h0] @ [w_ih|w_hh]^T + b ; LSTM elementwise fused in registers.
// 64 rows x 64 cols x 4 gates per block; 2-phase double-buffered staging.
// ---------------------------------------------------------------------------
__global__ __launch_bounds__(256) void gates_lstm_kernel(
    const unsigned short* __restrict__ Xb,   // [N,256] bf16
    const unsigned short* __restrict__ H0b,  // [N,256] bf16
    const unsigned short* __restrict__ Wih,  // [1024][256] bf16
    const unsigned short* __restrict__ Whh,  // [1024][256] bf16
    const float* __restrict__ b_ih, const float* __restrict__ b_hh,
    const float* __restrict__ c0,            // [N,256] fp32
    float* __restrict__ h1o, float* __restrict__ c1o,  // fp32 outputs
    unsigned short* __restrict__ rb)         // relu(h1) bf16 [N,256]
{
  __shared__ alignas(16) unsigned short As[2][2048];
  __shared__ alignas(16) unsigned short Bs[2][4][2048];
  int t = threadIdx.x, wave = t >> 6, lane = t & 63;
  int m0 = blockIdx.x * 64, cb = blockIdx.y * 64;
  int srow = lane & 15, schunk = lane >> 4;

  f32x4 acc[4][4] = {};

  auto stage = [&](int b, int kt){
    const unsigned short* Abase = (kt < 256) ? (Xb + kt) : (H0b + (kt - 256));
    const unsigned short* Wbase = (kt < 256) ? (Wih + kt) : (Whh + (kt - 256));
    async16(Abase + (size_t)(m0 + wave * 16 + srow) * 256 + schunk * 8, &As[b][wave << 9]);
#pragma unroll
    for (int g = 0; g < 4; ++g)
      async16(Wbase + (size_t)(g * 256 + cb + wave * 16 + srow) * 256 + schunk * 8,
              &Bs[b][g][wave << 9]);
  };
  int fo = (schunk << 7) + (srow << 3);
  auto compute = [&](int b){
    bf16x8 a = *(const bf16x8*)&As[b][(wave << 9) + fo];
#pragma unroll
    for (int g = 0; g < 4; ++g){
#pragma unroll
      for (int j = 0; j < 4; ++j){
        bf16x8 bb = *(const bf16x8*)&Bs[b][g][(j << 9) + fo];
        acc[g][j] = __builtin_amdgcn_mfma_f32_16x16x32_bf16(a, bb, acc[g][j], 0, 0, 0);
      }
    }
  };

  stage(0, 0);
  __syncthreads();
  int cur = 0;
  for (int kt = 32; kt < 512; kt += 32){
    stage(cur ^ 1, kt);
    compute(cur);
    __syncthreads();
    cur ^= 1;
  }
  compute(cur);

  int coll = lane & 15, rq = lane >> 4;
#pragma unroll
  for (int j = 0; j < 4; ++j){
    int col = cb + j * 16 + coll;
    float bi  = b_ih[col]       + b_hh[col];
    float bff = b_ih[256 + col] + b_hh[256 + col];
    float bg  = b_ih[512 + col] + b_hh[512 + col];
    float bo  = b_ih[768 + col] + b_hh[768 + col];
#pragma unroll
    for (int r = 0; r < 4; ++r){
      int node = m0 + wave * 16 + rq * 4 + r;
      size_t off = (size_t)node * 256 + col;
      float iv = sigm(acc[0][j][r] + bi);
      float fv = sigm(acc[1][j][r] + bff);
      float gv = tanhf(acc[2][j][r] + bg);
      float ov = sigm(acc[3][j][r] + bo);
      float cv = fv * c0[off] + iv * gv;
      float hv = ov * tanhf(cv);
      h1o[off] = hv;
      c1o[off] = cv;
      rb[off] = f2b(fmaxf(hv, 0.f));
    }
  }
}

// ---------------------------------------------------------------------------
// counting sort by dst: hist -> scan -> scatter
// ---------------------------------------------------------------------------
__global__ __launch_bounds__(256) void hist_kernel(
    const int* __restrict__ dst, int* __restrict__ hist)
{
  int e = blockIdx.x * 256 + threadIdx.x;
  atomicAdd(&hist[dst[e]], 1);
}

__global__ __launch_bounds__(256) void scan1_kernel(
    const int* __restrict__ hist, int* __restrict__ offs, int* __restrict__ bsum)
{
  __shared__ int s[256];
  int b = blockIdx.x, t = threadIdx.x;
  int v = hist[b * 256 + t];
  s[t] = v; __syncthreads();
  for (int d = 1; d < 256; d <<= 1){
    int x = (t >= d) ? s[t - d] : 0;
    __syncthreads();
    s[t] += x;
    __syncthreads();
  }
  offs[b * 256 + t] = s[t] - v;
  if (t == 255) bsum[b] = s[255];
}

__global__ __launch_bounds__(256) void scan2_kernel(int* __restrict__ bsum){
  __shared__ int s[256];
  int t = threadIdx.x;
  int v = bsum[t];
  s[t] = v; __syncthreads();
  for (int d = 1; d < 256; d <<= 1){
    int x = (t >= d) ? s[t - d] : 0;
    __syncthreads();
    s[t] += x;
    __syncthreads();
  }
  bsum[t] = s[t] - v;
}

__global__ __launch_bounds__(256) void scan3_kernel(
    int* __restrict__ offs, const int* __restrict__ bsum, int* __restrict__ cursor)
{
  int i = blockIdx.x * 256 + threadIdx.x;
  int v = offs[i] + bsum[blockIdx.x];
  offs[i] = v;
  cursor[i] = v;
}

__global__ __launch_bounds__(256) void scatter_kernel(
    const int* __restrict__ src, const int* __restrict__ dst,
    int* __restrict__ cursor, int* __restrict__ sorted_src)
{
  int e = blockIdx.x * 256 + threadIdx.x;
  int d = dst[e];
  int pos = atomicAdd(&cursor[d], 1);
  sorted_src[pos] = src[e];
}

// ---------------------------------------------------------------------------
// per-node edge aggregation: Hsum[n] = sum_{e in edges(n)} relu(P[src_e]+Q[n])
// one wave per node, 4 dims/lane. No atomics; src rows graph-local (L2-hot).
// ---------------------------------------------------------------------------
__global__ __launch_bounds__(256) void edge_agg_kernel(
    const unsigned short* __restrict__ P,    // [N,256] bf16
    const unsigned short* __restrict__ Q,    // [N,256] bf16 (bias folded in)
    const int* __restrict__ sorted_src,
    const int* __restrict__ offs,
    const int* __restrict__ cnt,
    unsigned short* __restrict__ Hsum)       // [N,256] bf16
{
  int t = threadIdx.x;
  int n = (blockIdx.x << 2) + (t >> 6);
  int lane = t & 63;
  int d0 = lane * 4;
  int off = offs[n], c = cnt[n];
  ushort4 qv = *(const ushort4*)&Q[(size_t)n * 256 + d0];
  float q0 = bf2f(qv.x), q1 = bf2f(qv.y), q2 = bf2f(qv.z), q3 = bf2f(qv.w);
  float a0 = 0.f, a1 = 0.f, a2 = 0.f, a3 = 0.f;
  for (int i = 0; i < c; ++i){
    int s = sorted_src[off + i];
    ushort4 pv = *(const ushort4*)&P[(size_t)s * 256 + d0];
    a0 += fmaxf(bf2f(pv.x) + q0, 0.f);
    a1 += fmaxf(bf2f(pv.y) + q1, 0.f);
    a2 += fmaxf(bf2f(pv.z) + q2, 0.f);
    a3 += fmaxf(bf2f(pv.w) + q3, 0.f);
  }
  ushort4 o; o.x = f2b(a0); o.y = f2b(a1); o.z = f2b(a2); o.w = f2b(a3);
  *(ushort4*)&Hsum[(size_t)n * 256 + d0] = o;
}

// ---------------------------------------------------------------------------
// readout layer 2: logits[N,8] = rh[N,256] @ wr2[8,256]^T + br2  (fp32 out)
// ---------------------------------------------------------------------------
__global__ __launch_bounds__(256) void logits_kernel(
    const unsigned short* __restrict__ rh,
    const unsigned short* __restrict__ wr2b,
    const float* __restrict__ br2,
    float* __restrict__ out)
{
  __shared__ alignas(16) unsigned short W[2048];
  int t = threadIdx.x;
  *(uint4*)&W[t * 8] = *(const uint4*)&wr2b[t * 8];
  __syncthreads();
  int node = blockIdx.x * 32 + (t >> 3);
  int o = t & 7;
  const unsigned short* r = rh + (size_t)node * 256;
  float s = br2[o];
#pragma unroll
  for (int k = 0; k < 256; k += 8){
    uint4 av = *(const uint4*)&r[k];
    const unsigned short* ap = (const unsigned short*)&av;
#pragma unroll
    for (int i = 0; i < 8; ++i) s += bf2f(ap[i]) * bf2f(W[o * 256 + k + i]);
  }
  out[(size_t)node * 8 + o] = s;
}

// ---------------------------------------------------------------------------
extern "C" void kernel_launch(void* const* d_in, const int* in_sizes, int n_in,
                              void* d_out, int out_size, void* d_ws, size_t ws_size,
                              hipStream_t stream)
{
  (void)in_sizes; (void)n_in; (void)out_size; (void)ws_size;
  const float* obs = (const float*)d_in[0];
  const float* h0  = (const float*)d_in[1];
  const float* c0  = (const float*)d_in[2];
  const int*   src = (const int*)d_in[3];
  const int*   dst = (const int*)d_in[4];
  const float* w1a = (const float*)d_in[5];
  const float* b1a = (const float*)d_in[6];
  const float* w1b = (const float*)d_in[7];
  const float* b1b = (const float*)d_in[8];
  const float* wih = (const float*)d_in[9];
  const float* bih = (const float*)d_in[10];
  const float* whh = (const float*)d_in[11];
  const float* bhh = (const float*)d_in[12];
  const float* w1  = (const float*)d_in[13];
  const float* b1  = (const float*)d_in[14];
  const float* we  = (const float*)d_in[15];
  const float* be  = (const float*)d_in[16];
  const float* we2 = (const float*)d_in[17];
  const float* be2 = (const float*)d_in[18];
  const float* wn  = (const float*)d_in[19];
  const float* bn  = (const float*)d_in[20];
  const float* wn2 = (const float*)d_in[21];
  const float* bn2 = (const float*)d_in[22];
  const float* wr  = (const float*)d_in[23];
  const float* br  = (const float*)d_in[24];
  const float* wr2 = (const float*)d_in[25];
  const float* br2 = (const float*)d_in[26];

  char* ws = (char*)d_ws;
  typedef unsigned short u16;
  // bf16 weight copies + sort scratch
  u16* w1a_b = (u16*)(ws + 0);
  u16* w1b_b = (u16*)(ws + 262144);
  u16* wih_b = (u16*)(ws + 524288);
  u16* whh_b = (u16*)(ws + 1048576);
  u16* w1_b  = (u16*)(ws + 1572864);
  u16* we_b  = (u16*)(ws + 1638400);
  u16* we2_b = (u16*)(ws + 1769472);
  u16* wn_b  = (u16*)(ws + 1835008);
  u16* wn2_b = (u16*)(ws + 1966080);
  u16* wr_b  = (u16*)(ws + 2031616);
  u16* wr2_b = (u16*)(ws + 2097152);
  float* zbias = (float*)(ws + 2101248);        // 512 fp32 zeros
  int* hist    = (int*)(ws + 2103296);          // [65536] = deg
  int* offs    = (int*)(ws + 2365440);          // [65536]
  int* cursor  = (int*)(ws + 2627584);          // [65536]
  int* bsum    = (int*)(ws + 2889728);          // [256]
  int* ssrc    = (int*)(ws + 2890752);          // sorted_src [524288]

  // aliased activation regions
  char* RA = ws + 5242880;    // 33.5MB: obs_b -> x_b -> P -> nf2
  char* RB = ws + 38797312;   // 33.5MB: h0_b -> Hsum -> hidn -> rh
  char* RY = ws + 72351744;   // 67MB:   y1 -> [rb->Q | ninp]

  u16* obs_b = (u16*)RA;
  u16* x_b   = (u16*)RA;
  u16* P     = (u16*)RA;
  u16* nf2   = (u16*)RA;
  u16* h0_b  = (u16*)RB;
  u16* Hsum  = (u16*)RB;
  u16* hidn  = (u16*)RB;
  u16* rh    = (u16*)RB;
  u16* y1    = (u16*)RY;
  u16* rb    = (u16*)RY;
  u16* Q     = (u16*)RY;
  u16* ninp  = (u16*)(RY + 33554432);

  float* logits = (float*)d_out;
  float* h1o = logits + (size_t)NN * 8;
  float* c1o = h1o + (size_t)NN * 256;

  // 0) zero-init scratch
  (void)hipMemsetAsync(zbias, 0, 2048, stream);
  (void)hipMemsetAsync(hist, 0, 65536 * 4, stream);

  // 1) convert fp32 -> bf16
  ConvArgs ca;
  const float* ss[13] = {obs, h0, w1a, w1b, wih, whh, w1, we, we2, wn, wn2, wr, wr2};
  u16* dd[13] = {obs_b, h0_b, w1a_b, w1b_b, wih_b, whh_b, w1_b, we_b, we2_b, wn_b, wn2_b, wr_b, wr2_b};
  int nn[13] = {NN*256, NN*256, 512*256, 256*512, 1024*256, 1024*256, 128*256,
                256*256, 128*256, 256*256, 128*256, 256*128, 8*256};
  for (int i = 0; i < 13; ++i){ ca.s[i]=ss[i]; ca.d[i]=dd[i]; ca.n4[i]=nn[i]/4; }
  ca.cnt = 13;
  convert_kernel<<<2048, 256, 0, stream>>>(ca);

  // 2) counting sort of edges by dst (independent of GEMM chain)
  hist_kernel<<<NE/256, 256, 0, stream>>>(dst, hist);
  scan1_kernel<<<256, 256, 0, stream>>>(hist, offs, bsum);
  scan2_kernel<<<1, 256, 0, stream>>>(bsum);
  scan3_kernel<<<256, 256, 0, stream>>>(offs, bsum, cursor);
  scatter_kernel<<<NE/256, 256, 0, stream>>>(src, dst, cursor, ssrc);

  // 3) y1 = relu(obs @ w1a^T + b1a)   [N,512]
  gemm_kernel<1,0><<<dim3(NN/128, 4), 256, 0, stream>>>(obs_b, 256, w1a_b, 256, 256, b1a, nullptr, y1, 512);
  // 4) x = y1 @ w1b^T + b1b           [N,256]
  gemm_kernel<0,0><<<dim3(NN/128, 2), 256, 0, stream>>>(y1, 512, w1b_b, 512, 512, b1b, nullptr, x_b, 256);
  // 5) gates + LSTM fused -> h1, c1 (fp32 out), rb = relu(h1) bf16
  gates_lstm_kernel<<<dim3(NN/64, 4), 256, 0, stream>>>(
      x_b, h0_b, wih_b, whh_b, bih, bhh, c0, h1o, c1o, rb);
  // 6) nf = rb @ w1^T + b1 -> ninp cols 0..127 (ldc=256)
  gemm_kernel<0,0><<<dim3(NN/128, 1), 256, 0, stream>>>(rb, 256, w1_b, 256, 256, b1, nullptr, ninp, 256);
  // 7) P = nf @ we_L^T (zero bias)    [N,256], K=128
  gemm_kernel<0,0><<<dim3(NN/128, 2), 256, 0, stream>>>(ninp, 256, we_b, 256, 128, zbias, nullptr, P, 256);
  // 8) Q = nf @ we_R^T + be           [N,256], K=128
  gemm_kernel<0,0><<<dim3(NN/128, 2), 256, 0, stream>>>(ninp, 256, we_b + 128, 256, 128, be, nullptr, Q, 256);
  // 9) Hsum[n] = sum over edges relu(P[src]+Q[n])
  edge_agg_kernel<<<NN/4, 256, 0, stream>>>(P, Q, ssrc, offs, hist, Hsum);
  // 10) agg = Hsum @ we2^T + deg*be2 -> ninp cols 128..255
  gemm_kernel<0,1><<<dim3(NN/128, 1), 256, 0, stream>>>(Hsum, 256, we2_b, 256, 256, be2, hist, ninp + 128, 256);
  // 11) hidn = relu(ninp @ wn^T + bn)  [N,256]
  gemm_kernel<1,0><<<dim3(NN/128, 2), 256, 0, stream>>>(ninp, 256, wn_b, 256, 256, bn, nullptr, hidn, 256);
  // 12) nf2 = hidn @ wn2^T + bn2       [N,128]
  gemm_kernel<0,0><<<dim3(NN/128, 1), 256, 0, stream>>>(hidn, 256, wn2_b, 256, 256, bn2, nullptr, nf2, 128);
  // 13) rh = relu(nf2 @ wr^T + br)     [N,256]
  gemm_kernel<1,0><<<dim3(NN/128, 2), 256, 0, stream>>>(nf2, 128, wr_b, 128, 128, br, nullptr, rh, 256);
  // 14) logits = rh @ wr2^T + br2      [N,8] fp32
  logits_kernel<<<NN/32, 256, 0, stream>>>(rh, wr2_b, br2, logits);
}